// Round 16
// baseline (145.142 us; speedup 1.0000x reference)
//
#include <hip/hip_runtime.h>
#include <hip/hip_bf16.h>

#define HID 128
#define OUTC 64
#define INC 3
#define BCAP 64        // bucket capacity per node (storage only; degree is exact)
#define OVF_CAP 8192   // overflow edge list capacity (expected usage: 0)
#define NT 64          // nodes per block in hidden GEMM
#define NCBMAX 256     // max coarse buckets (N<=65535 -> NCB<=256)
#define CAP8K 8192     // slots per coarse bucket in part[] (mean 4082, 64 sigma headroom)
#define KPT 8          // edges per thread in place2
#define EPT 4          // legacy path

static __device__ __forceinline__ unsigned short f2bf(float f) {
    __hip_bfloat16 b = __float2bfloat16(f);
    return *reinterpret_cast<unsigned short*>(&b);
}
static __device__ __forceinline__ float bf2f(unsigned short u) {
    __hip_bfloat16 b = *reinterpret_cast<__hip_bfloat16*>(&u);
    return __bfloat162float(b);
}

// ================= capacity-based counting-sort bucket build (N <= 65535 path) =================
// [proven rounds 11-15]

__global__ __launch_bounds__(256) void place2_kernel(const int* __restrict__ src,
                                                     const int* __restrict__ dst, int E, int NCB,
                                                     int* __restrict__ cbcur,
                                                     unsigned int* __restrict__ part,
                                                     int* __restrict__ ovf, int* __restrict__ ovf_cnt) {
    __shared__ int lhist[NCBMAX];
    __shared__ int lbase[NCBMAX];
    int t = threadIdx.x;
    int s0 = blockIdx.x * (256 * KPT);
    for (int i = t; i < NCBMAX; i += 256) lhist[i] = 0;
    __syncthreads();

    unsigned pk[KPT];
    int cbv[KPT];
    bool val[KPT];
#pragma unroll
    for (int i = 0; i < KPT; ++i) {
        int e = s0 + t + i * 256;                 // coalesced
        val[i] = (e < E);
        if (val[i]) {
            int d = dst[e], s = src[e];
            cbv[i] = d >> 8;
            pk[i] = (unsigned)s | ((unsigned)(d & 255) << 16);
            atomicAdd(&lhist[cbv[i]], 1);
        }
    }
    __syncthreads();
    for (int i = t; i < NCB; i += 256) {
        int c = lhist[i];
        lbase[i] = c ? atomicAdd(&cbcur[i], c) : 0;   // reserve contiguous range
        lhist[i] = 0;                                  // reuse as local offset
    }
    __syncthreads();
#pragma unroll
    for (int i = 0; i < KPT; ++i) {
        if (val[i]) {
            int cb = cbv[i];
            int p = atomicAdd(&lhist[cb], 1);
            int slot = lbase[cb] + p;
            if (slot < CAP8K) {
                part[(size_t)cb * CAP8K + slot] = pk[i];
            } else {                                   // impossible in practice; exact fallback
                int o = atomicAdd(ovf_cnt, 1);
                if (o < OVF_CAP) {
                    ovf[2 * o] = (int)(pk[i] & 0xFFFF);
                    ovf[2 * o + 1] = cb * 256 + (int)((pk[i] >> 16) & 0xFF);
                }
            }
        }
    }
}

__global__ __launch_bounds__(256) void bin_kernel(const unsigned int* __restrict__ part,
                                                  const int* __restrict__ cbcur,
                                                  const float* __restrict__ x, int N,
                                                  int* __restrict__ cursor,
                                                  unsigned short* __restrict__ bucket,
                                                  float4* __restrict__ z4,
                                                  int* __restrict__ ovf, int* __restrict__ ovf_cnt) {
    __shared__ int lcnt[256];
    __shared__ unsigned short lbuck[256 * BCAP];   // 32 KB
    int cb = blockIdx.x, t = threadIdx.x;
    lcnt[t] = 0;
    __syncthreads();
    int cnt = cbcur[cb];
    cnt = cnt < CAP8K ? cnt : CAP8K;
    size_t start = (size_t)cb * CAP8K;
    for (int i = t; i < cnt; i += 256) {
        unsigned pk = part[start + i];
        int s = pk & 0xFFFF;
        int ln = (pk >> 16) & 0xFF;
        int p = atomicAdd(&lcnt[ln], 1);
        if (p < BCAP) {
            lbuck[ln * BCAP + p] = (unsigned short)s;
        } else {
            int o = atomicAdd(ovf_cnt, 1);
            if (o < OVF_CAP) { ovf[2 * o] = s; ovf[2 * o + 1] = cb * 256 + ln; }
        }
    }
    __syncthreads();
    int d = cb * 256 + t;
    if (d < N) {
        int deg = lcnt[t];                         // exact degree (incl. >BCAP spill)
        cursor[d] = deg;
        float dd = rsqrtf((float)(deg + 1));       // +1 = self loop
        z4[d] = make_float4(dd * x[3 * d], dd * x[3 * d + 1], dd * x[3 * d + 2], dd);
    }
    const uint4* lsrc = (const uint4*)lbuck;
    uint4* gdst = (uint4*)(bucket + (size_t)cb * 256 * BCAP);
    for (int i = t; i < (256 * BCAP * 2) / 16; i += 256) gdst[i] = lsrc[i];  // dense copy
}

// ================= legacy path (N > 65535): atomic fill + z4 =================

template <typename IT>
__global__ void fill_bucket_kernel(const int* __restrict__ src, const int* __restrict__ dst, int E,
                                   int T, int* __restrict__ cursor, IT* __restrict__ bucket,
                                   int* __restrict__ ovf, int* __restrict__ ovf_cnt) {
    int tid = blockIdx.x * blockDim.x + threadIdx.x;
    int d[EPT], s[EPT], p[EPT];
    bool v[EPT];
#pragma unroll
    for (int k = 0; k < EPT; ++k) {
        int e = tid + k * T;
        v[k] = (e < E);
        d[k] = v[k] ? dst[e] : 0;
        s[k] = v[k] ? src[e] : 0;
    }
#pragma unroll
    for (int k = 0; k < EPT; ++k)
        if (v[k]) p[k] = atomicAdd(&cursor[d[k]], 1);
#pragma unroll
    for (int k = 0; k < EPT; ++k) {
        if (v[k]) {
            if (p[k] < BCAP) {
                bucket[(size_t)d[k] * BCAP + p[k]] = (IT)s[k];
            } else {
                int o = atomicAdd(ovf_cnt, 1);
                if (o < OVF_CAP) { ovf[2 * o] = s[k]; ovf[2 * o + 1] = d[k]; }
            }
        }
    }
}

__global__ void z4_kernel(const float* __restrict__ x, const int* __restrict__ cursor,
                          float4* __restrict__ z4, int N) {
    int i = blockIdx.x * blockDim.x + threadIdx.x;
    if (i < N) {
        float dd = rsqrtf((float)(cursor[i] + 1));
        z4[i] = make_float4(dd * x[3 * i], dd * x[3 * i + 1], dd * x[3 * i + 2], dd);
    }
}

// ==== fused hidden: layer-1 gather + relu(u@W1+b1) @ W2 GEMM, bf16 out (split A/B tables) ====

template <typename IT>
__global__ __launch_bounds__(256) void hidden_kernel(const IT* __restrict__ bucket,
                                                     const int* __restrict__ cursor,
                                                     const float4* __restrict__ z4,
                                                     const float* __restrict__ W1,
                                                     const float* __restrict__ b1,
                                                     const float* __restrict__ W2,
                                                     unsigned short* __restrict__ hsA,
                                                     unsigned short* __restrict__ hsB, int N,
                                                     const int* __restrict__ ovf,
                                                     const int* __restrict__ ovf_cnt) {
    __shared__ float h_s[HID][NT];       // 32 KB, k-major; first 192 floats alias u_s in stage 1
    __shared__ float w_s[HID * OUTC];    // 32 KB
    float* u_s = &h_s[0][0];             // [64][3] agg parking, 768 B
    int t = threadIdx.x;
    int base = blockIdx.x * NT;

    for (int i = t; i < HID * OUTC; i += 256) w_s[i] = W2[i];

    // stage 1a: gather agg for the block's 64 nodes
    {
        int g = (t & 63) & 15;           // node group within wave
        int r = (t & 63) >> 4;           // 0..3 split of the bucket list
        int n = (t >> 6) * 16 + g;       // wave w owns nodes w*16..w*16+15
        int d = base + n;
        float p0 = 0.f, p1 = 0.f, p2 = 0.f;
        if (d < N) {
            int cnt = cursor[d];
            cnt = cnt < BCAP ? cnt : BCAP;
            for (int k = r; k < cnt; k += 4) {
                int s = (int)bucket[(size_t)d * BCAP + k];
                float4 zv = z4[s];
                p0 += zv.x; p1 += zv.y; p2 += zv.z;
            }
        }
        // combine the 4 per-node partials (lanes l, l^16, l^32, l^48)
        p0 += __shfl_xor(p0, 16, 64); p0 += __shfl_xor(p0, 32, 64);
        p1 += __shfl_xor(p1, 16, 64); p1 += __shfl_xor(p1, 32, 64);
        p2 += __shfl_xor(p2, 16, 64); p2 += __shfl_xor(p2, 32, 64);
        if (r == 0 && d < N) {
            int oc = *ovf_cnt;                        // broadcast load; 0 in practice
            if (oc > 0) {
                oc = oc < OVF_CAP ? oc : OVF_CAP;
                for (int i = 0; i < oc; ++i) {
                    if (ovf[2 * i + 1] == d) {
                        float4 zs = z4[ovf[2 * i]];
                        p0 += zs.x; p1 += zs.y; p2 += zs.z;
                    }
                }
            }
            u_s[n * 3 + 0] = p0;
            u_s[n * 3 + 1] = p1;
            u_s[n * 3 + 2] = p2;
        }
    }
    __syncthreads();

    // stage 1b: u into registers (4 threads per node read the same agg)
    int n = t & 63;
    int d = base + n;
    float u0 = 0.f, u1 = 0.f, u2 = 0.f;
    if (d < N) {
        float a0 = u_s[n * 3], a1 = u_s[n * 3 + 1], a2 = u_s[n * 3 + 2];
        float4 zv = z4[d];
        float dd = zv.w;
        u0 = dd * (a0 + zv.x);
        u1 = dd * (a1 + zv.y);
        u2 = dd * (a2 + zv.z);
    }
    __syncthreads();                     // all u_s reads done before h_s writes

    // stage 1c: h = relu(u @ W1 + b1)
    {
        int k0 = t >> 6;
#pragma unroll
        for (int i = 0; i < HID / 4; ++i) {
            int k = k0 + 4 * i;
            float v = u0 * W1[k] + u1 * W1[HID + k] + u2 * W1[2 * HID + k] + b1[k];
            h_s[k][n] = fmaxf(v, 0.f);
        }
    }
    __syncthreads();

    // stage 2: 16x16 thread grid, 4x4 register tile
    int tx = t & 15, ty = t >> 4;
    float acc[4][4] = {};
#pragma unroll 8
    for (int k = 0; k < HID; ++k) {
        float4 hv = *(const float4*)&h_s[k][ty * 4];
        float4 wv = *(const float4*)&w_s[k * OUTC + tx * 4];
        float hr[4] = {hv.x, hv.y, hv.z, hv.w};
        float wr[4] = {wv.x, wv.y, wv.z, wv.w};
#pragma unroll
        for (int r = 0; r < 4; ++r)
#pragma unroll
            for (int c = 0; c < 4; ++c) acc[r][c] = fmaf(hr[r], wr[c], acc[r][c]);
    }

    // epilogue: features tx*4..tx*4+3 -> half-table A (tx<8) or B (tx>=8)
    unsigned short* tb = (tx < 8) ? hsA : hsB;
    int txl = tx & 7;
#pragma unroll
    for (int r = 0; r < 4; ++r) {
        int nn = ty * 4 + r;
        int dd_i = base + nn;
        if (dd_i < N) {
            float dd = z4[dd_i].w;
            ushort4 o;
            o.x = f2bf(dd * acc[r][0]);
            o.y = f2bf(dd * acc[r][1]);
            o.z = f2bf(dd * acc[r][2]);
            o.w = f2bf(dd * acc[r][3]);
            *(ushort4*)&tb[(size_t)dd_i * 32 + txl * 4] = o;
        }
    }
}

// ======== layer-2 gather, one 32-feature half per dispatch (L2-footprint-blocked) ========
// half-table = N x 32 bf16 (3.2 MB @ N=50K) -> fits a 4 MB per-XCD L2. 8-lane groups,
// uint2 loads (4 features/lane), 32 nodes/block; LDS-broadcast indices; no cross-lane ops.

#define ACC4(u)                                                        \
    do {                                                               \
        a0 += bf2f((u).x & 0xFFFF); a1 += bf2f((u).x >> 16);           \
        a2 += bf2f((u).y & 0xFFFF); a3 += bf2f((u).y >> 16);           \
    } while (0)

template <typename IT>
__global__ __launch_bounds__(256) void gather2_kernel(const int* __restrict__ cursor,
                                                      const IT* __restrict__ bucket,
                                                      const uint2* __restrict__ hsv,
                                                      const float4* __restrict__ z4,
                                                      const float* __restrict__ b2,
                                                      float* __restrict__ out, int N, int foff,
                                                      const int* __restrict__ ovf,
                                                      const int* __restrict__ ovf_cnt) {
    __shared__ int slist[32 * BCAP];                  // 8 KB: 32 nodes' source lists
    int t = threadIdx.x;
    int base = blockIdx.x * 32;                       // 32 nodes per block
    int lim = (N - base) * BCAP;                      // entries available
    int total = 32 * BCAP;
    if (lim > total) lim = total;
    for (int i = t; i < lim; i += 256) slist[i] = (int)bucket[(size_t)base * BCAP + i];
    __syncthreads();

    int g = t >> 3;                                   // group 0..31 -> node
    int q = t & 7;                                    // lane -> feature quad (foff+4q..+3)
    int d = base + g;
    if (d >= N) return;
    int cnt = cursor[d];
    cnt = cnt < BCAP ? cnt : BCAP;
    const int* my = &slist[g * BCAP];
    float a0 = 0.f, a1 = 0.f, a2 = 0.f, a3 = 0.f;
    int k = 0;
    for (; k + 8 <= cnt; k += 8) {                    // 8 independent half-row loads in flight
        uint2 u0 = hsv[(size_t)my[k]     * 8 + q];
        uint2 u1 = hsv[(size_t)my[k + 1] * 8 + q];
        uint2 u2 = hsv[(size_t)my[k + 2] * 8 + q];
        uint2 u3 = hsv[(size_t)my[k + 3] * 8 + q];
        uint2 u4 = hsv[(size_t)my[k + 4] * 8 + q];
        uint2 u5 = hsv[(size_t)my[k + 5] * 8 + q];
        uint2 u6 = hsv[(size_t)my[k + 6] * 8 + q];
        uint2 u7 = hsv[(size_t)my[k + 7] * 8 + q];
        ACC4(u0); ACC4(u1); ACC4(u2); ACC4(u3);
        ACC4(u4); ACC4(u5); ACC4(u6); ACC4(u7);
    }
    for (; k + 4 <= cnt; k += 4) {
        uint2 u0 = hsv[(size_t)my[k]     * 8 + q];
        uint2 u1 = hsv[(size_t)my[k + 1] * 8 + q];
        uint2 u2 = hsv[(size_t)my[k + 2] * 8 + q];
        uint2 u3 = hsv[(size_t)my[k + 3] * 8 + q];
        ACC4(u0); ACC4(u1); ACC4(u2); ACC4(u3);
    }
    for (; k < cnt; ++k) {
        uint2 u = hsv[(size_t)my[k] * 8 + q];
        ACC4(u);
    }
    int oc = *ovf_cnt;                                // broadcast load; 0 in practice
    if (oc > 0) {
        oc = oc < OVF_CAP ? oc : OVF_CAP;
        for (int i = 0; i < oc; ++i) {
            if (ovf[2 * i + 1] == d) {
                uint2 u = hsv[(size_t)ovf[2 * i] * 8 + q];
                ACC4(u);
            }
        }
    }
    uint2 us = hsv[(size_t)d * 8 + q];                // self loop
    float dd = z4[d].w;
    float4 bb = *(const float4*)&b2[foff + 4 * q];
    float4 o;
    o.x = dd * (a0 + bf2f(us.x & 0xFFFF)) + bb.x;
    o.y = dd * (a1 + bf2f(us.x >> 16)) + bb.y;
    o.z = dd * (a2 + bf2f(us.y & 0xFFFF)) + bb.z;
    o.w = dd * (a3 + bf2f(us.y >> 16)) + bb.w;
    *(float4*)&out[(size_t)d * OUTC + foff + 4 * q] = o;   // 128B coalesced per node-half
}

static inline size_t align256(size_t v) { return (v + 255) & ~(size_t)255; }

extern "C" void kernel_launch(void* const* d_in, const int* in_sizes, int n_in,
                              void* d_out, int out_size, void* d_ws, size_t ws_size,
                              hipStream_t stream) {
    const float* x  = (const float*)d_in[0];
    const int*   ei = (const int*)d_in[1];
    const float* W1 = (const float*)d_in[2];
    const float* b1 = (const float*)d_in[3];
    const float* W2 = (const float*)d_in[4];
    const float* b2 = (const float*)d_in[5];
    float* out = (float*)d_out;

    const int N = in_sizes[0] / INC;
    const int E = in_sizes[1] / 2;
    const int* src = ei;
    const int* dst = ei + E;
    const bool u16 = (N <= 65535);
    const int NCB = (N + 255) >> 8;

    char* ws = (char*)d_ws;
    size_t off = 0;
    int*    cursor  = (int*)(ws + off);    off += align256((size_t)N * 4);
    float4* z4      = (float4*)(ws + off); off += align256((size_t)N * 16);
    int*    cbcur   = (int*)(ws + off);    off += (size_t)NCBMAX * 4;      // zeroed with ovf_cnt
    int*    ovf_cnt = (int*)(ws + off);    off += 256;
    int*    ovf     = (int*)(ws + off);    off += (size_t)OVF_CAP * 8;
    unsigned int* part = (unsigned int*)(ws + off);
    off += align256(u16 ? (size_t)NCB * CAP8K * 4 : 0);
    void*   bucket  = (void*)(ws + off);
    off += align256(u16 ? (size_t)NCB * 256 * BCAP * 2 : (size_t)N * BCAP * 4);
    unsigned short* hsA = (unsigned short*)(ws + off); off += align256((size_t)N * 32 * 2);
    unsigned short* hsB = (unsigned short*)(ws + off); off += align256((size_t)N * 32 * 2);

    const int B = 256;

    if (u16) {
        hipMemsetAsync(cbcur, 0, (size_t)NCBMAX * 4 + 256, stream);        // cbcur + ovf_cnt
        int NB = (E + 256 * KPT - 1) / (256 * KPT);
        place2_kernel<<<NB, B, 0, stream>>>(src, dst, E, NCB, cbcur, part, ovf, ovf_cnt);
        bin_kernel<<<NCB, B, 0, stream>>>(part, cbcur, x, N, cursor,
                                          (unsigned short*)bucket, z4, ovf, ovf_cnt);
    } else {
        hipMemsetAsync(cursor, 0, (size_t)N * sizeof(int), stream);
        hipMemsetAsync(ovf_cnt, 0, 64, stream);
        int grid = (E + B * EPT - 1) / (B * EPT);
        int T = grid * B;
        fill_bucket_kernel<int><<<grid, B, 0, stream>>>(src, dst, E, T, cursor, (int*)bucket,
                                                        ovf, ovf_cnt);
        z4_kernel<<<(N + B - 1) / B, B, 0, stream>>>(x, cursor, z4, N);
    }

    // ---- fused layer-1 gather + hidden GEMM (bf16 out into split A/B half-tables) ----
    if (u16)
        hidden_kernel<unsigned short><<<(N + NT - 1) / NT, 256, 0, stream>>>(
            (const unsigned short*)bucket, cursor, z4, W1, b1, W2, hsA, hsB, N, ovf, ovf_cnt);
    else
        hidden_kernel<int><<<(N + NT - 1) / NT, 256, 0, stream>>>(
            (const int*)bucket, cursor, z4, W1, b1, W2, hsA, hsB, N, ovf, ovf_cnt);

    // ---- layer 2 gather: two L2-footprint-blocked passes (features 0..31, then 32..63) ----
    int g2grid = (N + 31) / 32;
    if (u16) {
        gather2_kernel<unsigned short><<<g2grid, B, 0, stream>>>(
            cursor, (const unsigned short*)bucket, (const uint2*)hsA, z4, b2, out, N, 0,
            ovf, ovf_cnt);
        gather2_kernel<unsigned short><<<g2grid, B, 0, stream>>>(
            cursor, (const unsigned short*)bucket, (const uint2*)hsB, z4, b2, out, N, 32,
            ovf, ovf_cnt);
    } else {
        gather2_kernel<int><<<g2grid, B, 0, stream>>>(
            cursor, (const int*)bucket, (const uint2*)hsA, z4, b2, out, N, 0, ovf, ovf_cnt);
        gather2_kernel<int><<<g2grid, B, 0, stream>>>(
            cursor, (const int*)bucket, (const uint2*)hsB, z4, b2, out, N, 32, ovf, ovf_cnt);
    }
}

// Round 17
// 137.755 us; speedup vs baseline: 1.0536x; 1.0536x over previous
//
#include <hip/hip_runtime.h>
#include <hip/hip_bf16.h>

#define HID 128
#define OUTC 64
#define INC 3
#define BCAP 64        // bucket capacity per node (storage only; degree is exact)
#define OVF_CAP 8192   // overflow edge list capacity (expected usage: 0)
#define NT 64          // nodes per block in hidden GEMM
#define NCBMAX 256     // max coarse buckets (N<=65535 -> NCB<=256)
#define CAP8K 8192     // slots per coarse bucket in part[] (mean 4082, 64 sigma headroom)
#define KPT 16         // edges per thread in place2 (16 coalesced loads in flight)
#define EPT 4          // legacy path

static __device__ __forceinline__ unsigned short f2bf(float f) {
    __hip_bfloat16 b = __float2bfloat16(f);
    return *reinterpret_cast<unsigned short*>(&b);
}
static __device__ __forceinline__ float bf2f(unsigned short u) {
    __hip_bfloat16 b = *reinterpret_cast<__hip_bfloat16*>(&u);
    return __bfloat162float(b);
}

// ================= capacity-based counting-sort bucket build (N <= 65535 path) =================
// [proven rounds 11-15; KPT raised 8->16]

__global__ __launch_bounds__(256) void place2_kernel(const int* __restrict__ src,
                                                     const int* __restrict__ dst, int E, int NCB,
                                                     int* __restrict__ cbcur,
                                                     unsigned int* __restrict__ part,
                                                     int* __restrict__ ovf, int* __restrict__ ovf_cnt) {
    __shared__ int lhist[NCBMAX];
    __shared__ int lbase[NCBMAX];
    int t = threadIdx.x;
    int s0 = blockIdx.x * (256 * KPT);
    for (int i = t; i < NCBMAX; i += 256) lhist[i] = 0;
    __syncthreads();

    unsigned pk[KPT];
    int cbv[KPT];
    bool val[KPT];
#pragma unroll
    for (int i = 0; i < KPT; ++i) {
        int e = s0 + t + i * 256;                 // coalesced
        val[i] = (e < E);
        if (val[i]) {
            int d = dst[e], s = src[e];
            cbv[i] = d >> 8;
            pk[i] = (unsigned)s | ((unsigned)(d & 255) << 16);
            atomicAdd(&lhist[cbv[i]], 1);
        }
    }
    __syncthreads();
    for (int i = t; i < NCB; i += 256) {
        int c = lhist[i];
        lbase[i] = c ? atomicAdd(&cbcur[i], c) : 0;   // reserve contiguous range
        lhist[i] = 0;                                  // reuse as local offset
    }
    __syncthreads();
#pragma unroll
    for (int i = 0; i < KPT; ++i) {
        if (val[i]) {
            int cb = cbv[i];
            int p = atomicAdd(&lhist[cb], 1);
            int slot = lbase[cb] + p;
            if (slot < CAP8K) {
                part[(size_t)cb * CAP8K + slot] = pk[i];
            } else {                                   // impossible in practice; exact fallback
                int o = atomicAdd(ovf_cnt, 1);
                if (o < OVF_CAP) {
                    ovf[2 * o] = (int)(pk[i] & 0xFFFF);
                    ovf[2 * o + 1] = cb * 256 + (int)((pk[i] >> 16) & 0xFF);
                }
            }
        }
    }
}

__global__ __launch_bounds__(256) void bin_kernel(const unsigned int* __restrict__ part,
                                                  const int* __restrict__ cbcur,
                                                  const float* __restrict__ x, int N,
                                                  int* __restrict__ cursor,
                                                  unsigned short* __restrict__ bucket,
                                                  float4* __restrict__ z4,
                                                  int* __restrict__ ovf, int* __restrict__ ovf_cnt) {
    __shared__ int lcnt[256];
    __shared__ unsigned short lbuck[256 * BCAP];   // 32 KB
    int cb = blockIdx.x, t = threadIdx.x;
    lcnt[t] = 0;
    __syncthreads();
    int cnt = cbcur[cb];
    cnt = cnt < CAP8K ? cnt : CAP8K;
    size_t start = (size_t)cb * CAP8K;
    for (int i = t; i < cnt; i += 256) {
        unsigned pk = part[start + i];
        int s = pk & 0xFFFF;
        int ln = (pk >> 16) & 0xFF;
        int p = atomicAdd(&lcnt[ln], 1);
        if (p < BCAP) {
            lbuck[ln * BCAP + p] = (unsigned short)s;
        } else {
            int o = atomicAdd(ovf_cnt, 1);
            if (o < OVF_CAP) { ovf[2 * o] = s; ovf[2 * o + 1] = cb * 256 + ln; }
        }
    }
    __syncthreads();
    int d = cb * 256 + t;
    if (d < N) {
        int deg = lcnt[t];                         // exact degree (incl. >BCAP spill)
        cursor[d] = deg;
        float dd = rsqrtf((float)(deg + 1));       // +1 = self loop
        z4[d] = make_float4(dd * x[3 * d], dd * x[3 * d + 1], dd * x[3 * d + 2], dd);
    }
    const uint4* lsrc = (const uint4*)lbuck;
    uint4* gdst = (uint4*)(bucket + (size_t)cb * 256 * BCAP);
    for (int i = t; i < (256 * BCAP * 2) / 16; i += 256) gdst[i] = lsrc[i];  // dense copy
}

// ================= legacy path (N > 65535): atomic fill + z4 =================

template <typename IT>
__global__ void fill_bucket_kernel(const int* __restrict__ src, const int* __restrict__ dst, int E,
                                   int T, int* __restrict__ cursor, IT* __restrict__ bucket,
                                   int* __restrict__ ovf, int* __restrict__ ovf_cnt) {
    int tid = blockIdx.x * blockDim.x + threadIdx.x;
    int d[EPT], s[EPT], p[EPT];
    bool v[EPT];
#pragma unroll
    for (int k = 0; k < EPT; ++k) {
        int e = tid + k * T;
        v[k] = (e < E);
        d[k] = v[k] ? dst[e] : 0;
        s[k] = v[k] ? src[e] : 0;
    }
#pragma unroll
    for (int k = 0; k < EPT; ++k)
        if (v[k]) p[k] = atomicAdd(&cursor[d[k]], 1);
#pragma unroll
    for (int k = 0; k < EPT; ++k) {
        if (v[k]) {
            if (p[k] < BCAP) {
                bucket[(size_t)d[k] * BCAP + p[k]] = (IT)s[k];
            } else {
                int o = atomicAdd(ovf_cnt, 1);
                if (o < OVF_CAP) { ovf[2 * o] = s[k]; ovf[2 * o + 1] = d[k]; }
            }
        }
    }
}

__global__ void z4_kernel(const float* __restrict__ x, const int* __restrict__ cursor,
                          float4* __restrict__ z4, int N) {
    int i = blockIdx.x * blockDim.x + threadIdx.x;
    if (i < N) {
        float dd = rsqrtf((float)(cursor[i] + 1));
        z4[i] = make_float4(dd * x[3 * i], dd * x[3 * i + 1], dd * x[3 * i + 2], dd);
    }
}

// ==== fused hidden: layer-1 gather + relu(u@W1+b1) @ W2 GEMM, bf16 out   [proven round 14] ====

template <typename IT>
__global__ __launch_bounds__(256) void hidden_kernel(const IT* __restrict__ bucket,
                                                     const int* __restrict__ cursor,
                                                     const float4* __restrict__ z4,
                                                     const float* __restrict__ W1,
                                                     const float* __restrict__ b1,
                                                     const float* __restrict__ W2,
                                                     unsigned short* __restrict__ hs2b, int N,
                                                     const int* __restrict__ ovf,
                                                     const int* __restrict__ ovf_cnt) {
    __shared__ float h_s[HID][NT];       // 32 KB, k-major; first 192 floats alias u_s in stage 1
    __shared__ float w_s[HID * OUTC];    // 32 KB
    float* u_s = &h_s[0][0];             // [64][3] agg parking, 768 B
    int t = threadIdx.x;
    int base = blockIdx.x * NT;

    for (int i = t; i < HID * OUTC; i += 256) w_s[i] = W2[i];

    // stage 1a: gather agg for the block's 64 nodes
    {
        int g = (t & 63) & 15;           // node group within wave
        int r = (t & 63) >> 4;           // 0..3 split of the bucket list
        int n = (t >> 6) * 16 + g;       // wave w owns nodes w*16..w*16+15
        int d = base + n;
        float p0 = 0.f, p1 = 0.f, p2 = 0.f;
        if (d < N) {
            int cnt = cursor[d];
            cnt = cnt < BCAP ? cnt : BCAP;
            for (int k = r; k < cnt; k += 4) {
                int s = (int)bucket[(size_t)d * BCAP + k];
                float4 zv = z4[s];
                p0 += zv.x; p1 += zv.y; p2 += zv.z;
            }
        }
        // combine the 4 per-node partials (lanes l, l^16, l^32, l^48)
        p0 += __shfl_xor(p0, 16, 64); p0 += __shfl_xor(p0, 32, 64);
        p1 += __shfl_xor(p1, 16, 64); p1 += __shfl_xor(p1, 32, 64);
        p2 += __shfl_xor(p2, 16, 64); p2 += __shfl_xor(p2, 32, 64);
        if (r == 0 && d < N) {
            int oc = *ovf_cnt;                        // broadcast load; 0 in practice
            if (oc > 0) {
                oc = oc < OVF_CAP ? oc : OVF_CAP;
                for (int i = 0; i < oc; ++i) {
                    if (ovf[2 * i + 1] == d) {
                        float4 zs = z4[ovf[2 * i]];
                        p0 += zs.x; p1 += zs.y; p2 += zs.z;
                    }
                }
            }
            u_s[n * 3 + 0] = p0;
            u_s[n * 3 + 1] = p1;
            u_s[n * 3 + 2] = p2;
        }
    }
    __syncthreads();

    // stage 1b: u into registers (4 threads per node read the same agg)
    int n = t & 63;
    int d = base + n;
    float u0 = 0.f, u1 = 0.f, u2 = 0.f;
    if (d < N) {
        float a0 = u_s[n * 3], a1 = u_s[n * 3 + 1], a2 = u_s[n * 3 + 2];
        float4 zv = z4[d];
        float dd = zv.w;
        u0 = dd * (a0 + zv.x);
        u1 = dd * (a1 + zv.y);
        u2 = dd * (a2 + zv.z);
    }
    __syncthreads();                     // all u_s reads done before h_s writes

    // stage 1c: h = relu(u @ W1 + b1)
    {
        int k0 = t >> 6;
#pragma unroll
        for (int i = 0; i < HID / 4; ++i) {
            int k = k0 + 4 * i;
            float v = u0 * W1[k] + u1 * W1[HID + k] + u2 * W1[2 * HID + k] + b1[k];
            h_s[k][n] = fmaxf(v, 0.f);
        }
    }
    __syncthreads();

    // stage 2: 16x16 thread grid, 4x4 register tile
    int tx = t & 15, ty = t >> 4;
    float acc[4][4] = {};
#pragma unroll 8
    for (int k = 0; k < HID; ++k) {
        float4 hv = *(const float4*)&h_s[k][ty * 4];
        float4 wv = *(const float4*)&w_s[k * OUTC + tx * 4];
        float hr[4] = {hv.x, hv.y, hv.z, hv.w};
        float wr[4] = {wv.x, wv.y, wv.z, wv.w};
#pragma unroll
        for (int r = 0; r < 4; ++r)
#pragma unroll
            for (int c = 0; c < 4; ++c) acc[r][c] = fmaf(hr[r], wr[c], acc[r][c]);
    }

#pragma unroll
    for (int r = 0; r < 4; ++r) {
        int nn = ty * 4 + r;
        int dd_i = base + nn;
        if (dd_i < N) {
            float dd = z4[dd_i].w;
            ushort4 o;
            o.x = f2bf(dd * acc[r][0]);
            o.y = f2bf(dd * acc[r][1]);
            o.z = f2bf(dd * acc[r][2]);
            o.w = f2bf(dd * acc[r][3]);
            *(ushort4*)&hs2b[(size_t)dd_i * OUTC + tx * 4] = o;
        }
    }
}

// ======== layer-2 gather: LDS-staged lists, 8 nodes/wave, uint4 (8-feature) loads ========
// [proven round 15; no cross-lane ops; LDS-broadcast indices; l2-ovf inlined]

#define ACC8(u)                                                        \
    do {                                                               \
        a0 += bf2f((u).x & 0xFFFF); a1 += bf2f((u).x >> 16);           \
        a2 += bf2f((u).y & 0xFFFF); a3 += bf2f((u).y >> 16);           \
        a4 += bf2f((u).z & 0xFFFF); a5 += bf2f((u).z >> 16);           \
        a6 += bf2f((u).w & 0xFFFF); a7 += bf2f((u).w >> 16);           \
    } while (0)

template <typename IT>
__global__ __launch_bounds__(256) void gather2_kernel(const int* __restrict__ cursor,
                                                      const IT* __restrict__ bucket,
                                                      const uint4* __restrict__ hs2q,
                                                      const float4* __restrict__ z4,
                                                      const float* __restrict__ b2,
                                                      float* __restrict__ out, int N,
                                                      const int* __restrict__ ovf,
                                                      const int* __restrict__ ovf_cnt) {
    __shared__ int slist[32 * BCAP];                  // 8 KB: 32 nodes' source lists
    int t = threadIdx.x;
    int base = blockIdx.x * 32;                       // 32 nodes per block
    int lim = (N - base) * BCAP;                      // entries available
    int total = 32 * BCAP;
    if (lim > total) lim = total;
    for (int i = t; i < lim; i += 256) slist[i] = (int)bucket[(size_t)base * BCAP + i];
    __syncthreads();

    int g = t >> 3;                                   // group 0..31 -> node
    int q = t & 7;                                    // lane -> feature octet (8q..8q+7)
    int d = base + g;
    if (d >= N) return;
    int cnt = cursor[d];
    cnt = cnt < BCAP ? cnt : BCAP;
    const int* my = &slist[g * BCAP];
    float a0 = 0.f, a1 = 0.f, a2 = 0.f, a3 = 0.f, a4 = 0.f, a5 = 0.f, a6 = 0.f, a7 = 0.f;
    int k = 0;
    for (; k + 8 <= cnt; k += 8) {                    // 8 independent 16B row loads in flight
        uint4 u0 = hs2q[(size_t)my[k]     * 8 + q];
        uint4 u1 = hs2q[(size_t)my[k + 1] * 8 + q];
        uint4 u2 = hs2q[(size_t)my[k + 2] * 8 + q];
        uint4 u3 = hs2q[(size_t)my[k + 3] * 8 + q];
        uint4 u4 = hs2q[(size_t)my[k + 4] * 8 + q];
        uint4 u5 = hs2q[(size_t)my[k + 5] * 8 + q];
        uint4 u6 = hs2q[(size_t)my[k + 6] * 8 + q];
        uint4 u7 = hs2q[(size_t)my[k + 7] * 8 + q];
        ACC8(u0); ACC8(u1); ACC8(u2); ACC8(u3);
        ACC8(u4); ACC8(u5); ACC8(u6); ACC8(u7);
    }
    for (; k + 4 <= cnt; k += 4) {
        uint4 u0 = hs2q[(size_t)my[k]     * 8 + q];
        uint4 u1 = hs2q[(size_t)my[k + 1] * 8 + q];
        uint4 u2 = hs2q[(size_t)my[k + 2] * 8 + q];
        uint4 u3 = hs2q[(size_t)my[k + 3] * 8 + q];
        ACC8(u0); ACC8(u1); ACC8(u2); ACC8(u3);
    }
    for (; k < cnt; ++k) {
        uint4 u = hs2q[(size_t)my[k] * 8 + q];
        ACC8(u);
    }
    int oc = *ovf_cnt;                                // broadcast load; 0 in practice
    if (oc > 0) {
        oc = oc < OVF_CAP ? oc : OVF_CAP;
        for (int i = 0; i < oc; ++i) {
            if (ovf[2 * i + 1] == d) {
                uint4 u = hs2q[(size_t)ovf[2 * i] * 8 + q];
                ACC8(u);
            }
        }
    }
    uint4 us = hs2q[(size_t)d * 8 + q];               // self loop
    float dd = z4[d].w;
    float4 bbl = *(const float4*)&b2[8 * q];
    float4 bbh = *(const float4*)&b2[8 * q + 4];
    float4 ol, oh;
    ol.x = dd * (a0 + bf2f(us.x & 0xFFFF)) + bbl.x;
    ol.y = dd * (a1 + bf2f(us.x >> 16)) + bbl.y;
    ol.z = dd * (a2 + bf2f(us.y & 0xFFFF)) + bbl.z;
    ol.w = dd * (a3 + bf2f(us.y >> 16)) + bbl.w;
    oh.x = dd * (a4 + bf2f(us.z & 0xFFFF)) + bbh.x;
    oh.y = dd * (a5 + bf2f(us.z >> 16)) + bbh.y;
    oh.z = dd * (a6 + bf2f(us.w & 0xFFFF)) + bbh.z;
    oh.w = dd * (a7 + bf2f(us.w >> 16)) + bbh.w;
    *(float4*)&out[(size_t)d * OUTC + 8 * q] = ol;    // 256B coalesced per node
    *(float4*)&out[(size_t)d * OUTC + 8 * q + 4] = oh;
}

static inline size_t align256(size_t v) { return (v + 255) & ~(size_t)255; }

extern "C" void kernel_launch(void* const* d_in, const int* in_sizes, int n_in,
                              void* d_out, int out_size, void* d_ws, size_t ws_size,
                              hipStream_t stream) {
    const float* x  = (const float*)d_in[0];
    const int*   ei = (const int*)d_in[1];
    const float* W1 = (const float*)d_in[2];
    const float* b1 = (const float*)d_in[3];
    const float* W2 = (const float*)d_in[4];
    const float* b2 = (const float*)d_in[5];
    float* out = (float*)d_out;

    const int N = in_sizes[0] / INC;
    const int E = in_sizes[1] / 2;
    const int* src = ei;
    const int* dst = ei + E;
    const bool u16 = (N <= 65535);
    const int NCB = (N + 255) >> 8;

    char* ws = (char*)d_ws;
    size_t off = 0;
    int*    cursor  = (int*)(ws + off);    off += align256((size_t)N * 4);
    float4* z4      = (float4*)(ws + off); off += align256((size_t)N * 16);
    int*    cbcur   = (int*)(ws + off);    off += (size_t)NCBMAX * 4;      // zeroed with ovf_cnt
    int*    ovf_cnt = (int*)(ws + off);    off += 256;
    int*    ovf     = (int*)(ws + off);    off += (size_t)OVF_CAP * 8;
    unsigned int* part = (unsigned int*)(ws + off);
    off += align256(u16 ? (size_t)NCB * CAP8K * 4 : 0);
    void*   bucket  = (void*)(ws + off);
    off += align256(u16 ? (size_t)NCB * 256 * BCAP * 2 : (size_t)N * BCAP * 4);
    unsigned short* hs2b = (unsigned short*)(ws + off); off += (size_t)N * OUTC * 2;
    const uint4* hs2q = (const uint4*)hs2b;

    const int B = 256;

    if (u16) {
        hipMemsetAsync(cbcur, 0, (size_t)NCBMAX * 4 + 256, stream);        // cbcur + ovf_cnt
        int NB = (E + 256 * KPT - 1) / (256 * KPT);
        place2_kernel<<<NB, B, 0, stream>>>(src, dst, E, NCB, cbcur, part, ovf, ovf_cnt);
        bin_kernel<<<NCB, B, 0, stream>>>(part, cbcur, x, N, cursor,
                                          (unsigned short*)bucket, z4, ovf, ovf_cnt);
    } else {
        hipMemsetAsync(cursor, 0, (size_t)N * sizeof(int), stream);
        hipMemsetAsync(ovf_cnt, 0, 64, stream);
        int grid = (E + B * EPT - 1) / (B * EPT);
        int T = grid * B;
        fill_bucket_kernel<int><<<grid, B, 0, stream>>>(src, dst, E, T, cursor, (int*)bucket,
                                                        ovf, ovf_cnt);
        z4_kernel<<<(N + B - 1) / B, B, 0, stream>>>(x, cursor, z4, N);
    }

    // ---- fused layer-1 gather + hidden GEMM (bf16 out; l1-ovf inlined) ----
    if (u16)
        hidden_kernel<unsigned short><<<(N + NT - 1) / NT, 256, 0, stream>>>(
            (const unsigned short*)bucket, cursor, z4, W1, b1, W2, hs2b, N, ovf, ovf_cnt);
    else
        hidden_kernel<int><<<(N + NT - 1) / NT, 256, 0, stream>>>(
            (const int*)bucket, cursor, z4, W1, b1, W2, hs2b, N, ovf, ovf_cnt);

    // ---- layer 2 gather (LDS-staged, 8 nodes/wave, uint4 loads; l2-ovf inlined) ----
    if (u16)
        gather2_kernel<unsigned short><<<(N + 31) / 32, B, 0, stream>>>(
            cursor, (const unsigned short*)bucket, hs2q, z4, b2, out, N, ovf, ovf_cnt);
    else
        gather2_kernel<int><<<(N + 31) / 32, B, 0, stream>>>(
            cursor, (const int*)bucket, hs2q, z4, b2, out, N, ovf, ovf_cnt);
}